// Round 7
// baseline (194.466 us; speedup 1.0000x reference)
//
#include <hip/hip_runtime.h>
#include <hip/hip_bf16.h>

#define B_  4
#define S_  2048
#define D_  640
#define H_  10
#define KD_ 64
// M = B_*S_ = 8192; QKV fused N = 3*H_*KD_ = 1920; K = 640

typedef __attribute__((ext_vector_type(8))) short  short8;
typedef __attribute__((ext_vector_type(4))) short  short4v;
typedef __attribute__((ext_vector_type(4))) float  floatx4;
typedef __attribute__((ext_vector_type(2))) unsigned int uint2v;

// scalar cheap RNE bf16 (finite inputs only).
static __device__ __forceinline__ short f2bf_fast(float f) {
    unsigned int u = __float_as_uint(f);
    u += 0x7fffu + ((u >> 16) & 1u);
    return (short)(u >> 16);
}
// packed pair via HIP intrinsic (maps to v_cvt_pk_bf16_f32 where available).
static __device__ __forceinline__ unsigned int pack2bf(float a, float b) {
    union { __hip_bfloat162 h; unsigned int u; } c;
    c.h = __float22bfloat162_rn(float2{a, b});
    return c.u;
}

// async global->LDS DMA, 16 B/lane: lane i lands at ldsbase + i*16.
static __device__ __forceinline__ void gload_lds16(const void* gp, void* lp) {
    __builtin_amdgcn_global_load_lds(
        (const __attribute__((address_space(1))) unsigned int*)gp,
        (__attribute__((address_space(3))) unsigned int*)lp, 16, 0, 0);
}

// ---------------------------------------------------------------------------
// Kernel 1: fused prep — pack_x (blocks [0,5120)), transpose_w [5120,6320),
// transpose_wo [6320,6720). Branches are WG-uniform.  (frozen)
// ---------------------------------------------------------------------------
__global__ __launch_bounds__(256) void prep(
        const float* __restrict__ x,
        const float* __restrict__ Wq, const float* __restrict__ Wk,
        const float* __restrict__ Wv, const float* __restrict__ Wo,
        short* __restrict__ xb, short* __restrict__ BigT,
        short* __restrict__ WoT) {
    __shared__ float tile[32][33];
    int bid = blockIdx.x;
    if (bid < 5120) {
        int idx = (bid * 256 + threadIdx.x) * 4;
        float4 v = *(const float4*)(x + idx);
        uint2v o;
        o[0] = pack2bf(v.x, v.y);
        o[1] = pack2bf(v.z, v.w);
        *(uint2v*)(xb + idx) = o;
    } else if (bid < 6320) {
        int flat = bid - 5120;
        int bz = flat / 40, rem = flat % 40;
        int by = rem >> 1, bxx = rem & 1;
        int w = bz / 10, h = bz % 10;
        const float* W = ((w == 0) ? Wq : (w == 1) ? Wk : Wv) + h * 640 * 64;
        short* out = BigT + (w * 640 + h * 64) * 640;
        int c0 = bxx * 32;   // kd tile
        int r0 = by * 32;    // d tile
        int tx = threadIdx.x & 31, ty = threadIdx.x >> 5;
        #pragma unroll
        for (int k = 0; k < 4; ++k)
            tile[ty + 8 * k][tx] = W[(r0 + ty + 8 * k) * 64 + c0 + tx];
        __syncthreads();
        #pragma unroll
        for (int k = 0; k < 4; ++k)
            out[(c0 + ty + 8 * k) * 640 + r0 + tx] = f2bf_fast(tile[tx][ty + 8 * k]);
    } else {
        int flat = bid - 6320;                 // (20,20)
        int c0 = (flat % 20) * 32;             // n tile
        int r0 = (flat / 20) * 32;             // f tile
        int tx = threadIdx.x & 31, ty = threadIdx.x >> 5;
        #pragma unroll
        for (int k = 0; k < 4; ++k)
            tile[ty + 8 * k][tx] = Wo[(r0 + ty + 8 * k) * 640 + c0 + tx];
        __syncthreads();
        #pragma unroll
        for (int k = 0; k < 4; ++k)
            WoT[(c0 + ty + 8 * k) * 640 + r0 + tx] = f2bf_fast(tile[tx][ty + 8 * k]);
    }
}

// ===========================================================================
// GEMM v2 core pattern (frozen control since R5/R6): 128-row tile, BK=32,
// double-buffered LDS, one __syncthreads() per K-iter, DMA-after-barrier.
// Vectorized epilogues via operand-order selection (R6).
// ===========================================================================

// ---------------------------------------------------------------------------
// Kernel 2: fused QKV projection GEMM.  Y(8192x1920) = X(8192x640) @ BigT^T.
// ---------------------------------------------------------------------------
__global__ __launch_bounds__(256) void qkv_gemm(
        const short* __restrict__ X, const short* __restrict__ BigT,
        short* __restrict__ qb, short* __restrict__ kb, short* __restrict__ vtb) {
    __shared__ __align__(16) short Ab[2][128][32];   // 16 KB
    __shared__ __align__(16) short Bb[2][128][32];   // 16 KB

    int wave = threadIdx.x >> 6;
    int lane = threadIdx.x & 63;
    int lq = lane & 15, quad = lane >> 4;
    int wm = (wave & 1) * 64, wn = (wave >> 1) * 64;

    // XCD swizzle: lin%8 = XCD; each XCD owns 8 contiguous M-tiles across all
    // N-tiles (per-XCD set ~3.7 MB fits 4 MB L2). Bijective (960%8==0).
    int lin = blockIdx.y * 64 + blockIdx.x;          // [0, 960)
    int tm = ((lin & 7) * 8 + ((lin >> 3) & 7)) * 128;
    int tn = (lin >> 6) * 128;

    // staging source addressing
    int srow = lane >> 2;                               // 0..15
    int schunk = (lane & 3) ^ ((lane >> 3) & 3);        // XOR by (row>>1)&3
    const short* Asrc0 = X    + (tm + wave * 32 + srow) * 640 + schunk * 8;
    const short* Bsrc0 = BigT + (tn + wave * 32 + srow) * 640 + schunk * 8;
    const short* Asrc1 = Asrc0 + 16 * 640;
    const short* Bsrc1 = Bsrc0 + 16 * 640;

    floatx4 acc[4][4];
    for (int a = 0; a < 4; ++a)
        for (int n = 0; n < 4; ++n)
            acc[a][n] = (floatx4){0.f, 0.f, 0.f, 0.f};

    int rsw = (lq >> 1) & 3;     // fragment-read XOR

    // prologue: stage k-slab 0 into buffer 0
    gload_lds16(Asrc0, &Ab[0][wave * 32][0]);
    gload_lds16(Asrc1, &Ab[0][wave * 32 + 16][0]);
    gload_lds16(Bsrc0, &Bb[0][wave * 32][0]);
    gload_lds16(Bsrc1, &Bb[0][wave * 32 + 16][0]);

    int p = 0;
    bool isV = (tn >= 1280);

    for (int k0 = 0; k0 < 640; k0 += 32) {
        __syncthreads();   // vmcnt(0) drain => buf[p] staged; buf[p^1] free
        if (k0 + 32 < 640) {
            int pn = p ^ 1;
            gload_lds16(Asrc0 + k0 + 32, &Ab[pn][wave * 32][0]);
            gload_lds16(Asrc1 + k0 + 32, &Ab[pn][wave * 32 + 16][0]);
            gload_lds16(Bsrc0 + k0 + 32, &Bb[pn][wave * 32][0]);
            gload_lds16(Bsrc1 + k0 + 32, &Bb[pn][wave * 32 + 16][0]);
        }

        short8 af[4], bf[4];
        #pragma unroll
        for (int t = 0; t < 4; ++t) {
            af[t] = *(const short8*)(&Ab[p][wm + t * 16 + lq][(quad ^ rsw) * 8]);
            bf[t] = *(const short8*)(&Bb[p][wn + t * 16 + lq][(quad ^ rsw) * 8]);
        }
        if (!isV) {
            // Q/K: SWAPPED -> acc[mt][nt]: col(lq)=m=s, row(quad*4+r)=n=kd
            #pragma unroll
            for (int mt = 0; mt < 4; ++mt)
                #pragma unroll
                for (int nt = 0; nt < 4; ++nt)
                    acc[mt][nt] = __builtin_amdgcn_mfma_f32_16x16x32_bf16(
                        bf[nt], af[mt], acc[mt][nt], 0, 0, 0);
        } else {
            // V: NORMAL -> acc[mt][nt]: col(lq)=n=kd, row(quad*4+r)=m=s
            #pragma unroll
            for (int mt = 0; mt < 4; ++mt)
                #pragma unroll
                for (int nt = 0; nt < 4; ++nt)
                    acc[mt][nt] = __builtin_amdgcn_mfma_f32_16x16x32_bf16(
                        af[mt], bf[nt], acc[mt][nt], 0, 0, 0);
        }
        p ^= 1;
    }

    if (!isV) {
        const float qscale = 0.18033688011112042f;  // (1/sqrt(64)) * log2(e)
        short* dst = (tn < 640) ? qb : kb;
        float scale = (tn < 640) ? qscale : 1.0f;
        #pragma unroll
        for (int nt = 0; nt < 4; ++nt) {
            int rem = (tn + wn + nt * 16) % 640;
            int hh = rem / 64;
            int kd0 = (rem % 64) + quad * 4;       // r runs along kd (contig)
            #pragma unroll
            for (int mt = 0; mt < 4; ++mt) {
                int m = tm + wm + mt * 16 + lq;    // s per lane
                int b = m >> 11, s = m & 2047;
                uint2v w;
                w[0] = pack2bf(acc[mt][nt][0] * scale, acc[mt][nt][1] * scale);
                w[1] = pack2bf(acc[mt][nt][2] * scale, acc[mt][nt][3] * scale);
                *(uint2v*)(dst + (((b * H_ + hh) * S_ + s) * KD_ + kd0)) = w;
            }
        }
    } else {
        #pragma unroll
        for (int nt = 0; nt < 4; ++nt) {
            int rem = (tn + wn + nt * 16) - 1280;   // within V range [0,640)
            int hh = rem / 64;
            int kd = (rem % 64) + lq;               // kd per lane
            #pragma unroll
            for (int mt = 0; mt < 4; ++mt) {
                int s = tm + wm + mt * 16 + quad * 4;  // r runs along s (contig)
                int b = s >> 11, s0 = s & 2047;
                uint2v w;
                w[0] = pack2bf(acc[mt][nt][0], acc[mt][nt][1]);
                w[1] = pack2bf(acc[mt][nt][2], acc[mt][nt][3]);
                *(uint2v*)(vtb + (((b * H_ + hh) * KD_ + kd) * (long)S_ + s0)) = w;
            }
        }
    }
}

// ---------------------------------------------------------------------------
// Kernel 3: flash attention v9 — T15-analog software pipeline.
// QK^T(t+1) computed CONCURRENTLY with softmax+PV(t): the MFMA+ds_read work
// of the next tile hides under the long exp2/cvt/permlane VALU section of
// the current tile (the two use disjoint registers and disjoint LDS
// buffers). K is prefetched one tile deeper than V (K 3-deep, V 2-deep).
// FIFO/vmcnt schedule (verified by simulation, in 4-B load units; each
// STAGE = 2 loads):
//   prologue: issue K0 V0 K1 V1 K2 (10) -> vmcnt(8) retires K0 -> QKT(0)
//   iter t (0..29): vmcnt(4) retires {V(t),K(t+1)}; barrier;
//     issue V(t+2) and (t<=28) K(t+3); compute QKT(t+1) || SMPV(t)
//   tail: vmcnt(2) retires {V30,K31}; QKT(31) || SMPV(30);
//         vmcnt(0) retires V31; SMPV(31)
// Buffer hazards: stage K(t+3)->Kbuf[t%3] (K(t) read at iter t-1, done);
// stage V(t+2)->Vbuf[(t+2)%3] != Vbuf[t%3] being read; all crossings are
// protected by the iteration barrier. Same DMA discipline class as v8
// (validated in THIS kernel); counts re-derived for the K/V split depth.
// ---------------------------------------------------------------------------
__global__ __launch_bounds__(256, 3) void attn(
        const short* __restrict__ qb, const short* __restrict__ kbuf,
        const short* __restrict__ vtb, short* __restrict__ zb) {
    __shared__ __align__(16) short Kbuf[3][64][64];      // 24 KB
    __shared__ __align__(16) short Vbuf[3][64][64];      // 24 KB

    int wave = threadIdx.x >> 6;
    int lane = threadIdx.x & 63;
    int lq = lane & 15, quad = lane >> 4;

    int bx = blockIdx.x;               // 640 = 8 xcd * 5 bh * 16 qtiles
    int xcd = bx & 7, slot = bx >> 3;
    int bh = xcd * 5 + (slot >> 4);
    int qt = slot & 15;
    int b = bh / 10, h = bh % 10;
    int q0 = qt * 128;

    const short* qp = qb + (b * H_ + h) * S_ * KD_;
    const short* kp = kbuf + (b * H_ + h) * S_ * KD_;
    const short* vp = vtb + (b * H_ + h) * KD_ * S_;

    int r8 = lane >> 3;
    int g  = (lane & 7) ^ r8;          // XOR-swizzled 16B group
    const short* kg0 = kp + (wave * 16 + r8) * 64 + g * 8;
    const short* kg1 = kp + (wave * 16 + 8 + r8) * 64 + g * 8;
    const short* vg0 = vp + (wave * 16 + r8) * (long)S_ + g * 8;
    const short* vg1 = vp + (wave * 16 + 8 + r8) * (long)S_ + g * 8;

    short8 qA0, qA1, qB0, qB1;
    {
        int rowA = q0 + wave * 32 + lq;
        qA0 = *(const short8*)(qp + rowA * 64 + quad * 8);
        qA1 = *(const short8*)(qp + rowA * 64 + 32 + quad * 8);
        qB0 = *(const short8*)(qp + (rowA + 16) * 64 + quad * 8);
        qB1 = *(const short8*)(qp + (rowA + 16) * 64 + 32 + quad * 8);
    }

    short8 ones;
    #pragma unroll
    for (int i = 0; i < 8; ++i) ones[i] = (short)0x3F80;   // bf16 1.0

    floatx4 OA[4], OB[4];   // O^T accum: col=m=lq, row=kd_local
    for (int n = 0; n < 4; ++n) {
        OA[n] = (floatx4){0.f, 0.f, 0.f, 0.f};
        OB[n] = (floatx4){0.f, 0.f, 0.f, 0.f};
    }
    floatx4 lsvA = (floatx4){0.f, 0.f, 0.f, 0.f};   // row-sum accum (replicated)
    floatx4 lsvB = (floatx4){0.f, 0.f, 0.f, 0.f};

    int sw = lq & 7;

    #define STAGE_K(tt, bi) do { \
        gload_lds16(kg0 + (tt) * 4096, &Kbuf[bi][wave * 16][0]); \
        gload_lds16(kg1 + (tt) * 4096, &Kbuf[bi][wave * 16 + 8][0]); \
    } while (0)
    #define STAGE_V(tt, bi) do { \
        gload_lds16(vg0 + (tt) * 64,   &Vbuf[bi][wave * 16][0]); \
        gload_lds16(vg1 + (tt) * 64,   &Vbuf[bi][wave * 16 + 8][0]); \
    } while (0)

    // QK^T for one 64-key tile from Kbase into dstA/dstB (4 floatx4 each).
    #define QKT(Kbase, dstA, dstB) do { \
        const short* Kb_ = (Kbase); \
        __builtin_amdgcn_s_setprio(1); \
        _Pragma("unroll") \
        for (int kblk = 0; kblk < 4; ++kblk) { \
            const short* krow = Kb_ + (kblk * 16 + lq) * 64; \
            short8 bk0 = *(const short8*)(krow + (quad ^ sw) * 8); \
            short8 bk1 = *(const short8*)(krow + ((quad + 4) ^ sw) * 8); \
            floatx4 zA = (floatx4){0.f, 0.f, 0.f, 0.f}; \
            zA = __builtin_amdgcn_mfma_f32_16x16x32_bf16(bk0, qA0, zA, 0, 0, 0); \
            dstA[kblk] = __builtin_amdgcn_mfma_f32_16x16x32_bf16(bk1, qA1, zA, 0, 0, 0); \
            floatx4 zB = (floatx4){0.f, 0.f, 0.f, 0.f}; \
            zB = __builtin_amdgcn_mfma_f32_16x16x32_bf16(bk0, qB0, zB, 0, 0, 0); \
            dstB[kblk] = __builtin_amdgcn_mfma_f32_16x16x32_bf16(bk1, qB1, zB, 0, 0, 0); \
        } \
        __builtin_amdgcn_s_setprio(0); \
    } while (0)

    // softmax + in-register P^T transpose + PV for one tile (scores in
    // srcA/srcB, V from Vbase). Accumulates OA/OB/lsvA/lsvB.
    #define SMPV(srcA, srcB, Vbase) do { \
        const short* Vb_ = (Vbase); \
        _Pragma("unroll") \
        for (int ts = 0; ts < 2; ++ts) { \
            int ka = ts * 2, kc = ts * 2 + 1; \
            unsigned int a00 = pack2bf(__builtin_amdgcn_exp2f(srcA[ka][0]), \
                                       __builtin_amdgcn_exp2f(srcA[ka][1])); \
            unsigned int a01 = pack2bf(__builtin_amdgcn_exp2f(srcA[ka][2]), \
                                       __builtin_amdgcn_exp2f(srcA[ka][3])); \
            unsigned int a10 = pack2bf(__builtin_amdgcn_exp2f(srcA[kc][0]), \
                                       __builtin_amdgcn_exp2f(srcA[kc][1])); \
            unsigned int a11 = pack2bf(__builtin_amdgcn_exp2f(srcA[kc][2]), \
                                       __builtin_amdgcn_exp2f(srcA[kc][3])); \
            uint2v sa0 = __builtin_amdgcn_permlane32_swap(a00, a10, false, false); \
            uint2v sa1 = __builtin_amdgcn_permlane32_swap(a01, a11, false, false); \
            uint2v wa02 = __builtin_amdgcn_permlane16_swap(sa0[0], sa0[1], false, false); \
            uint2v wa13 = __builtin_amdgcn_permlane16_swap(sa1[0], sa1[1], false, false); \
            union { unsigned int u[4]; short8 s8; } pfa; \
            pfa.u[0] = wa02[0]; pfa.u[1] = wa13[0]; \
            pfa.u[2] = wa02[1]; pfa.u[3] = wa13[1]; \
            short8 pfA = pfa.s8; \
            unsigned int b00 = pack2bf(__builtin_amdgcn_exp2f(srcB[ka][0]), \
                                       __builtin_amdgcn_exp2f(srcB[ka][1])); \
            unsigned int b01 = pack2bf(__builtin_amdgcn_exp2f(srcB[ka][2]), \
                                       __builtin_amdgcn_exp2f(srcB[ka][3])); \
            unsigned int b10 = pack2bf(__builtin_amdgcn_exp2f(srcB[kc][0]), \
                                       __builtin_amdgcn_exp2f(srcB[kc][1])); \
            unsigned int b11 = pack2bf(__builtin_amdgcn_exp2f(srcB[kc][2]), \
                                       __builtin_amdgcn_exp2f(srcB[kc][3])); \
            uint2v sb0 = __builtin_amdgcn_permlane32_swap(b00, b10, false, false); \
            uint2v sb1 = __builtin_amdgcn_permlane32_swap(b01, b11, false, false); \
            uint2v wb02 = __builtin_amdgcn_permlane16_swap(sb0[0], sb0[1], false, false); \
            uint2v wb13 = __builtin_amdgcn_permlane16_swap(sb1[0], sb1[1], false, false); \
            union { unsigned int u[4]; short8 s8; } pfb; \
            pfb.u[0] = wb02[0]; pfb.u[1] = wb13[0]; \
            pfb.u[2] = wb02[1]; pfb.u[3] = wb13[1]; \
            short8 pfB = pfb.s8; \
            __builtin_amdgcn_s_setprio(1); \
            lsvA = __builtin_amdgcn_mfma_f32_16x16x32_bf16(ones, pfA, lsvA, 0, 0, 0); \
            lsvB = __builtin_amdgcn_mfma_f32_16x16x32_bf16(ones, pfB, lsvB, 0, 0, 0); \
            _Pragma("unroll") \
            for (int db = 0; db < 4; ++db) { \
                const short* vrow = Vb_ + (db * 16 + lq) * 64; \
                short8 bv = *(const short8*)(vrow + ((ts * 4 + quad) ^ sw) * 8); \
                OA[db] = __builtin_amdgcn_mfma_f32_16x16x32_bf16(bv, pfA, OA[db], 0, 0, 0); \
                OB[db] = __builtin_amdgcn_mfma_f32_16x16x32_bf16(bv, pfB, OB[db], 0, 0, 0); \
            } \
            __builtin_amdgcn_s_setprio(0); \
        } \
    } while (0)

    floatx4 cA[4], cB[4], nA[4], nB[4];

    // prologue: K 3-deep, V 2-deep.  FIFO: K0 V0 K1 V1 K2 (10 loads).
    STAGE_K(0, 0);
    STAGE_V(0, 0);
    STAGE_K(1, 1);
    STAGE_V(1, 1);
    STAGE_K(2, 2);
    asm volatile("s_waitcnt vmcnt(8)\n\ts_barrier" ::: "memory");  // K0 landed
    QKT(&Kbuf[0][0][0], cA, cB);

    // main loop, 2-unrolled ping-pong (cur/nxt score regs, no copies).
    for (int t2 = 0; t2 < 30; t2 += 2) {
        {   // t = t2: retire {V(t),K(t+1)}; issue V(t+2), K(t+3)
            asm volatile("s_waitcnt vmcnt(4)\n\ts_barrier" ::: "memory");
            STAGE_V(t2 + 2, (t2 + 2) % 3);
            STAGE_K(t2 + 3, t2 % 3);          // (t2+3)%3 == t2%3
            QKT(&Kbuf[(t2 + 1) % 3][0][0], nA, nB);
            SMPV(cA, cB, &Vbuf[t2 % 3][0][0]);
        }
        {   // t = t2+1
            int t = t2 + 1;
            asm volatile("s_waitcnt vmcnt(4)\n\ts_barrier" ::: "memory");
            STAGE_V(t + 2, (t + 2) % 3);
            if (t <= 28) STAGE_K(t + 3, t % 3);
            QKT(&Kbuf[(t + 1) % 3][0][0], cA, cB);
            SMPV(nA, nB, &Vbuf[t % 3][0][0]);
        }
    }
    // after loop: cA/cB = scores(tile 30).  In flight: V30,K31,V31 (6 loads).
    asm volatile("s_waitcnt vmcnt(2)\n\ts_barrier" ::: "memory");  // V30,K31 in
    QKT(&Kbuf[1][0][0], nA, nB);          // tile 31 (31%3==1)
    SMPV(cA, cB, &Vbuf[0][0][0]);         // tile 30 (30%3==0)
    asm volatile("s_waitcnt vmcnt(0)\n\ts_barrier" ::: "memory");  // V31 in
    SMPV(nA, nB, &Vbuf[1][0][0]);         // tile 31 (31%3==1)

    #undef STAGE_K
    #undef STAGE_V
    #undef QKT
    #undef SMPV

    float invA = 1.0f / lsvA[0];
    float invB = 1.0f / lsvB[0];

    int sA = q0 + wave * 32 + lq;        // group A Q-row (lane-fixed)
    int sB = sA + 16;
    short* zrA = zb + (b * S_ + sA) * 640 + h * 64;
    short* zrB = zb + (b * S_ + sB) * 640 + h * 64;
    #pragma unroll
    for (int db = 0; db < 4; ++db) {
        uint2v za, zv;
        za[0] = pack2bf(OA[db][0] * invA, OA[db][1] * invA);
        za[1] = pack2bf(OA[db][2] * invA, OA[db][3] * invA);
        *(uint2v*)(zrA + db * 16 + quad * 4) = za;
        zv[0] = pack2bf(OB[db][0] * invB, OB[db][1] * invB);
        zv[1] = pack2bf(OB[db][2] * invB, OB[db][3] * invB);
        *(uint2v*)(zrB + db * 16 + quad * 4) = zv;
    }
}

// ---------------------------------------------------------------------------
// Kernel 4: output projection, 128(M)x64(N) tile, grid 640.  out = Z @ WoT^T.
// SWAPPED mfma -> r runs along contiguous out columns -> float4 stores.
// ---------------------------------------------------------------------------
__global__ __launch_bounds__(256) void out_gemm(
        const short* __restrict__ Z, const short* __restrict__ WoT,
        float* __restrict__ out) {
    __shared__ __align__(16) short Ab[2][128][32];   // 16 KB
    __shared__ __align__(16) short Bb[2][64][32];    //  8 KB

    int wave = threadIdx.x >> 6;
    int lane = threadIdx.x & 63;
    int lq = lane & 15, quad = lane >> 4;
    int wm = (wave & 1) * 64;        // M offset within tile
    int wn = (wave >> 1) * 32;       // N offset within tile

    int lin = blockIdx.y * 64 + blockIdx.x;          // [0, 640)
    int tm = ((lin & 7) * 8 + ((lin >> 3) & 7)) * 128;
    int tn = (lin >> 6) * 64;

    int srow = lane >> 2;
    int schunk = (lane & 3) ^ ((lane >> 3) & 3);
    const short* Asrc0 = Z   + (tm + wave * 32 + srow) * 640 + schunk * 8;
    const short* Asrc1 = Asrc0 + 16 * 640;
    const short* Bsrc0 = WoT + (tn + wave * 16 + srow) * 640 + schunk * 8;

    floatx4 acc[4][2];
    for (int a = 0; a < 4; ++a)
        for (int n = 0; n < 2; ++n)
            acc[a][n] = (floatx4){0.f, 0.f, 0.f, 0.f};

    int rsw = (lq >> 1) & 3;

    gload_lds16(Asrc0, &Ab[0][wave * 32][0]);
    gload_lds16(Asrc1, &Ab[0][wave * 32 + 16][0]);
    gload_lds16(Bsrc0, &Bb[0][wave * 16][0]);

    int p = 0;
    for (int k0 = 0; k0 < 640; k0 += 32) {
        __syncthreads();
        if (k0 + 32 < 640) {
            int pn = p ^ 1;
            gload_lds16(Asrc0 + k0 + 32, &Ab[pn][wave * 32][0]);
            gload_lds16(Asrc1 + k0 + 32, &Ab[pn][wave * 32 + 16][0]);
            gload_lds16(Bsrc0 + k0 + 32, &Bb[pn][wave * 16][0]);
        }

        short8 af[4], bf[2];
        #pragma unroll
        for (int t = 0; t < 4; ++t)
            af[t] = *(const short8*)(&Ab[p][wm + t * 16 + lq][(quad ^ rsw) * 8]);
        #pragma unroll
        for (int u = 0; u < 2; ++u)
            bf[u] = *(const short8*)(&Bb[p][wn + u * 16 + lq][(quad ^ rsw) * 8]);
        // SWAPPED: col(lq)=m, row(quad*4+r)=n
        #pragma unroll
        for (int mt = 0; mt < 4; ++mt)
            #pragma unroll
            for (int nt = 0; nt < 2; ++nt)
                acc[mt][nt] = __builtin_amdgcn_mfma_f32_16x16x32_bf16(
                    bf[nt], af[mt], acc[mt][nt], 0, 0, 0);
        p ^= 1;
    }

    #pragma unroll
    for (int mt = 0; mt < 4; ++mt) {
        int m = tm + wm + mt * 16 + lq;
        #pragma unroll
        for (int nt = 0; nt < 2; ++nt) {
            int n0 = tn + wn + nt * 16 + quad * 4;
            float4 v;
            v.x = acc[mt][nt][0];
            v.y = acc[mt][nt][1];
            v.z = acc[mt][nt][2];
            v.w = acc[mt][nt][3];
            *(float4*)(out + m * 640 + n0) = v;
        }
    }
}

// ---------------------------------------------------------------------------
extern "C" void kernel_launch(void* const* d_in, const int* in_sizes, int n_in,
                              void* d_out, int out_size, void* d_ws, size_t ws_size,
                              hipStream_t stream) {
    const float* x  = (const float*)d_in[0];
    const float* Wq = (const float*)d_in[1];
    const float* Wk = (const float*)d_in[2];
    const float* Wv = (const float*)d_in[3];
    const float* Wo = (const float*)d_in[4];
    float* out = (float*)d_out;

    char* ws = (char*)d_ws;
    short* BigT = (short*)(ws);                    //  1920*640*2 = 2,457,600
    short* WoT  = (short*)(ws + 2457600);          //   640*640*2 =   819,200
    short* xb   = (short*)(ws + 3276800);          // 8192*640*2  = 10,485,760
    short* qb   = (short*)(ws + 13762560);
    short* kb   = (short*)(ws + 24248320);
    short* vtb  = (short*)(ws + 34734080);
    short* zb   = (short*)(ws + 45219840);         // end = 55,705,600 B

    prep<<<dim3(6720), dim3(256), 0, stream>>>(x, Wq, Wk, Wv, Wo, xb, BigT, WoT);
    qkv_gemm<<<dim3(64, 15), dim3(256), 0, stream>>>(xb, BigT, qb, kb, vtb);
    attn<<<dim3(640), dim3(256), 0, stream>>>(qb, kb, vtb, zb);
    out_gemm<<<dim3(64, 10), dim3(256), 0, stream>>>(zb, WoT, out);
}

// Round 8
// 192.537 us; speedup vs baseline: 1.0100x; 1.0100x over previous
//
#include <hip/hip_runtime.h>
#include <hip/hip_bf16.h>

#define B_  4
#define S_  2048
#define D_  640
#define H_  10
#define KD_ 64
// M = B_*S_ = 8192; QKV fused N = 3*H_*KD_ = 1920; K = 640

typedef __attribute__((ext_vector_type(8))) short  short8;
typedef __attribute__((ext_vector_type(4))) short  short4v;
typedef __attribute__((ext_vector_type(4))) float  floatx4;
typedef __attribute__((ext_vector_type(2))) unsigned int uint2v;
typedef __attribute__((ext_vector_type(4))) unsigned int uint4v;

// scalar cheap RNE bf16 (finite inputs only).
static __device__ __forceinline__ short f2bf_fast(float f) {
    unsigned int u = __float_as_uint(f);
    u += 0x7fffu + ((u >> 16) & 1u);
    return (short)(u >> 16);
}
// packed pair via HIP intrinsic (maps to v_cvt_pk_bf16_f32 where available).
static __device__ __forceinline__ unsigned int pack2bf(float a, float b) {
    union { __hip_bfloat162 h; unsigned int u; } c;
    c.h = __float22bfloat162_rn(float2{a, b});
    return c.u;
}
static __device__ __forceinline__ float bf2f(short v) {
    return __uint_as_float(((unsigned int)(unsigned short)v) << 16);
}

// async global->LDS DMA, 16 B/lane: lane i lands at ldsbase + i*16.
static __device__ __forceinline__ void gload_lds16(const void* gp, void* lp) {
    __builtin_amdgcn_global_load_lds(
        (const __attribute__((address_space(1))) unsigned int*)gp,
        (__attribute__((address_space(3))) unsigned int*)lp, 16, 0, 0);
}

// ---------------------------------------------------------------------------
// Kernel 1: fused prep — pack_x (blocks [0,5120)), transpose_w [5120,6320),
// transpose_wo [6320,6720). Branches are WG-uniform.  (frozen)
// ---------------------------------------------------------------------------
__global__ __launch_bounds__(256) void prep(
        const float* __restrict__ x,
        const float* __restrict__ Wq, const float* __restrict__ Wk,
        const float* __restrict__ Wv, const float* __restrict__ Wo,
        short* __restrict__ xb, short* __restrict__ BigT,
        short* __restrict__ WoT) {
    __shared__ float tile[32][33];
    int bid = blockIdx.x;
    if (bid < 5120) {
        int idx = (bid * 256 + threadIdx.x) * 4;
        float4 v = *(const float4*)(x + idx);
        uint2v o;
        o[0] = pack2bf(v.x, v.y);
        o[1] = pack2bf(v.z, v.w);
        *(uint2v*)(xb + idx) = o;
    } else if (bid < 6320) {
        int flat = bid - 5120;
        int bz = flat / 40, rem = flat % 40;
        int by = rem >> 1, bxx = rem & 1;
        int w = bz / 10, h = bz % 10;
        const float* W = ((w == 0) ? Wq : (w == 1) ? Wk : Wv) + h * 640 * 64;
        short* out = BigT + (w * 640 + h * 64) * 640;
        int c0 = bxx * 32;   // kd tile
        int r0 = by * 32;    // d tile
        int tx = threadIdx.x & 31, ty = threadIdx.x >> 5;
        #pragma unroll
        for (int k = 0; k < 4; ++k)
            tile[ty + 8 * k][tx] = W[(r0 + ty + 8 * k) * 64 + c0 + tx];
        __syncthreads();
        #pragma unroll
        for (int k = 0; k < 4; ++k)
            out[(c0 + ty + 8 * k) * 640 + r0 + tx] = f2bf_fast(tile[tx][ty + 8 * k]);
    } else {
        int flat = bid - 6320;                 // (20,20)
        int c0 = (flat % 20) * 32;             // n tile
        int r0 = (flat / 20) * 32;             // f tile
        int tx = threadIdx.x & 31, ty = threadIdx.x >> 5;
        #pragma unroll
        for (int k = 0; k < 4; ++k)
            tile[ty + 8 * k][tx] = Wo[(r0 + ty + 8 * k) * 640 + c0 + tx];
        __syncthreads();
        #pragma unroll
        for (int k = 0; k < 4; ++k)
            WoT[(c0 + ty + 8 * k) * 640 + r0 + tx] = f2bf_fast(tile[tx][ty + 8 * k]);
    }
}

// ===========================================================================
// GEMM v2 core pattern (frozen since R5/R6): 128-row tile, BK=32, double-
// buffered LDS, one __syncthreads() per K-iter, DMA-after-barrier.
// Vectorized epilogues via operand-order selection (R6, validated 2x).
// ===========================================================================

// ---------------------------------------------------------------------------
// Kernel 2: fused QKV projection GEMM.  Y(8192x1920) = X(8192x640) @ BigT^T.
// ---------------------------------------------------------------------------
__global__ __launch_bounds__(256) void qkv_gemm(
        const short* __restrict__ X, const short* __restrict__ BigT,
        short* __restrict__ qb, short* __restrict__ kb, short* __restrict__ vtb) {
    __shared__ __align__(16) short Ab[2][128][32];   // 16 KB
    __shared__ __align__(16) short Bb[2][128][32];   // 16 KB

    int wave = threadIdx.x >> 6;
    int lane = threadIdx.x & 63;
    int lq = lane & 15, quad = lane >> 4;
    int wm = (wave & 1) * 64, wn = (wave >> 1) * 64;

    // XCD swizzle: lin%8 = XCD; each XCD owns 8 contiguous M-tiles across all
    // N-tiles (per-XCD set ~3.7 MB fits 4 MB L2). Bijective (960%8==0).
    int lin = blockIdx.y * 64 + blockIdx.x;          // [0, 960)
    int tm = ((lin & 7) * 8 + ((lin >> 3) & 7)) * 128;
    int tn = (lin >> 6) * 128;

    // staging source addressing
    int srow = lane >> 2;                               // 0..15
    int schunk = (lane & 3) ^ ((lane >> 3) & 3);        // XOR by (row>>1)&3
    const short* Asrc0 = X    + (tm + wave * 32 + srow) * 640 + schunk * 8;
    const short* Bsrc0 = BigT + (tn + wave * 32 + srow) * 640 + schunk * 8;
    const short* Asrc1 = Asrc0 + 16 * 640;
    const short* Bsrc1 = Bsrc0 + 16 * 640;

    floatx4 acc[4][4];
    for (int a = 0; a < 4; ++a)
        for (int n = 0; n < 4; ++n)
            acc[a][n] = (floatx4){0.f, 0.f, 0.f, 0.f};

    int rsw = (lq >> 1) & 3;     // fragment-read XOR

    // prologue: stage k-slab 0 into buffer 0
    gload_lds16(Asrc0, &Ab[0][wave * 32][0]);
    gload_lds16(Asrc1, &Ab[0][wave * 32 + 16][0]);
    gload_lds16(Bsrc0, &Bb[0][wave * 32][0]);
    gload_lds16(Bsrc1, &Bb[0][wave * 32 + 16][0]);

    int p = 0;
    bool isV = (tn >= 1280);

    for (int k0 = 0; k0 < 640; k0 += 32) {
        __syncthreads();   // vmcnt(0) drain => buf[p] staged; buf[p^1] free
        if (k0 + 32 < 640) {
            int pn = p ^ 1;
            gload_lds16(Asrc0 + k0 + 32, &Ab[pn][wave * 32][0]);
            gload_lds16(Asrc1 + k0 + 32, &Ab[pn][wave * 32 + 16][0]);
            gload_lds16(Bsrc0 + k0 + 32, &Bb[pn][wave * 32][0]);
            gload_lds16(Bsrc1 + k0 + 32, &Bb[pn][wave * 32 + 16][0]);
        }

        short8 af[4], bf[4];
        #pragma unroll
        for (int t = 0; t < 4; ++t) {
            af[t] = *(const short8*)(&Ab[p][wm + t * 16 + lq][(quad ^ rsw) * 8]);
            bf[t] = *(const short8*)(&Bb[p][wn + t * 16 + lq][(quad ^ rsw) * 8]);
        }
        if (!isV) {
            // Q/K: SWAPPED -> acc[mt][nt]: col(lq)=m=s, row(quad*4+r)=n=kd
            #pragma unroll
            for (int mt = 0; mt < 4; ++mt)
                #pragma unroll
                for (int nt = 0; nt < 4; ++nt)
                    acc[mt][nt] = __builtin_amdgcn_mfma_f32_16x16x32_bf16(
                        bf[nt], af[mt], acc[mt][nt], 0, 0, 0);
        } else {
            // V: NORMAL -> acc[mt][nt]: col(lq)=n=kd, row(quad*4+r)=m=s
            #pragma unroll
            for (int mt = 0; mt < 4; ++mt)
                #pragma unroll
                for (int nt = 0; nt < 4; ++nt)
                    acc[mt][nt] = __builtin_amdgcn_mfma_f32_16x16x32_bf16(
                        af[mt], bf[nt], acc[mt][nt], 0, 0, 0);
        }
        p ^= 1;
    }

    if (!isV) {
        const float qscale = 0.18033688011112042f;  // (1/sqrt(64)) * log2(e)
        short* dst = (tn < 640) ? qb : kb;
        float scale = (tn < 640) ? qscale : 1.0f;
        #pragma unroll
        for (int nt = 0; nt < 4; ++nt) {
            int rem = (tn + wn + nt * 16) % 640;
            int hh = rem / 64;
            int kd0 = (rem % 64) + quad * 4;       // r runs along kd (contig)
            #pragma unroll
            for (int mt = 0; mt < 4; ++mt) {
                int m = tm + wm + mt * 16 + lq;    // s per lane
                int b = m >> 11, s = m & 2047;
                uint2v w;
                w[0] = pack2bf(acc[mt][nt][0] * scale, acc[mt][nt][1] * scale);
                w[1] = pack2bf(acc[mt][nt][2] * scale, acc[mt][nt][3] * scale);
                *(uint2v*)(dst + (((b * H_ + hh) * S_ + s) * KD_ + kd0)) = w;
            }
        }
    } else {
        #pragma unroll
        for (int nt = 0; nt < 4; ++nt) {
            int rem = (tn + wn + nt * 16) - 1280;   // within V range [0,640)
            int hh = rem / 64;
            int kd = (rem % 64) + lq;               // kd per lane
            #pragma unroll
            for (int mt = 0; mt < 4; ++mt) {
                int s = tm + wm + mt * 16 + quad * 4;  // r runs along s (contig)
                int b = s >> 11, s0 = s & 2047;
                uint2v w;
                w[0] = pack2bf(acc[mt][nt][0], acc[mt][nt][1]);
                w[1] = pack2bf(acc[mt][nt][2], acc[mt][nt][3]);
                *(uint2v*)(vtb + (((b * H_ + hh) * KD_ + kd) * (long)S_ + s0)) = w;
            }
        }
    }
}

// ---------------------------------------------------------------------------
// Kernel 3: flash attention v10 — SPLIT-KV on the R2-validated drain
// double-buffer structure (32 KB LDS -> 5 blocks/CU; grid 1280 = exactly
// 5 blocks/CU, 5 waves/SIMD — 2x the TLP of the 640-grid versions, with the
// per-wave structure (32 Q-rows, 36 MFMA per 16 ds_read) UNCHANGED).
// Each block handles keys [half*1024, half*1024+1024) = 16 tiles.
// No-max softmax => partials combine additively: write unnormalized O^T
// (bf16) to zp (half0 -> zb region, half1 -> xb region) + fp32 row-sums to
// lsvb (BigT region, dead after qkv_gemm). combine kernel finishes.
// ---------------------------------------------------------------------------
__global__ __launch_bounds__(256, 3) void attn(
        const short* __restrict__ qb, const short* __restrict__ kbuf,
        const short* __restrict__ vtb, short* __restrict__ zp0,
        short* __restrict__ zp1, float* __restrict__ lsvb) {
    __shared__ __align__(16) short Kbuf[2][64][64];      // 16 KB
    __shared__ __align__(16) short Vbuf[2][64][64];      // 16 KB

    int wave = threadIdx.x >> 6;
    int lane = threadIdx.x & 63;
    int lq = lane & 15, quad = lane >> 4;

    int bx = blockIdx.x;               // 1280 = 8 xcd * 5 bh * 16 qt * 2 half
    int xcd = bx & 7, slot = bx >> 3;  // slot in [0,160)
    int bh = xcd * 5 + (slot >> 5);
    int rest = slot & 31;
    int qt = rest >> 1;
    int half = rest & 1;
    int b = bh / 10, h = bh % 10;
    int q0 = qt * 128;

    const short* qp = qb + (b * H_ + h) * S_ * KD_;
    const short* kp = kbuf + (b * H_ + h) * S_ * KD_ + half * 1024 * KD_;
    const short* vp = vtb + (b * H_ + h) * KD_ * S_ + half * 1024;

    int r8 = lane >> 3;
    int g  = (lane & 7) ^ r8;          // XOR-swizzled 16B group
    const short* kg0 = kp + (wave * 16 + r8) * 64 + g * 8;
    const short* kg1 = kp + (wave * 16 + 8 + r8) * 64 + g * 8;
    const short* vg0 = vp + (wave * 16 + r8) * (long)S_ + g * 8;
    const short* vg1 = vp + (wave * 16 + 8 + r8) * (long)S_ + g * 8;

    short8 qA0, qA1, qB0, qB1;
    {
        int rowA = q0 + wave * 32 + lq;
        qA0 = *(const short8*)(qp + rowA * 64 + quad * 8);
        qA1 = *(const short8*)(qp + rowA * 64 + 32 + quad * 8);
        qB0 = *(const short8*)(qp + (rowA + 16) * 64 + quad * 8);
        qB1 = *(const short8*)(qp + (rowA + 16) * 64 + 32 + quad * 8);
    }

    short8 ones;
    #pragma unroll
    for (int i = 0; i < 8; ++i) ones[i] = (short)0x3F80;   // bf16 1.0

    floatx4 OA[4], OB[4];   // O^T accum: col=m=lq, row=kd_local
    for (int n = 0; n < 4; ++n) {
        OA[n] = (floatx4){0.f, 0.f, 0.f, 0.f};
        OB[n] = (floatx4){0.f, 0.f, 0.f, 0.f};
    }
    floatx4 lsvA = (floatx4){0.f, 0.f, 0.f, 0.f};   // row-sum accum (replicated)
    floatx4 lsvB = (floatx4){0.f, 0.f, 0.f, 0.f};

    gload_lds16(kg0, &Kbuf[0][wave * 16][0]);
    gload_lds16(kg1, &Kbuf[0][wave * 16 + 8][0]);
    gload_lds16(vg0, &Vbuf[0][wave * 16][0]);
    gload_lds16(vg1, &Vbuf[0][wave * 16 + 8][0]);

    int p = 0;
    int sw = lq & 7;

    for (int t0 = 0; t0 < 1024; t0 += 64) {
        __syncthreads();   // vmcnt(0) drain => buf[p] staged; buf[p^1] free

        if (t0 + 64 < 1024) {
            int pn = p ^ 1;
            gload_lds16(kg0 + (t0 + 64) * 64, &Kbuf[pn][wave * 16][0]);
            gload_lds16(kg1 + (t0 + 64) * 64, &Kbuf[pn][wave * 16 + 8][0]);
            gload_lds16(vg0 + (t0 + 64),      &Vbuf[pn][wave * 16][0]);
            gload_lds16(vg1 + (t0 + 64),      &Vbuf[pn][wave * 16 + 8][0]);
        }

        const short* Kb = &Kbuf[p][0][0];
        const short* Vb = &Vbuf[p][0][0];

        // ---- S^T = K·Q^T per 16-key block (K frags shared by A and B) ----
        floatx4 sTA[4], sTB[4];
        __builtin_amdgcn_s_setprio(1);
        #pragma unroll
        for (int kblk = 0; kblk < 4; ++kblk) {
            const short* krow = Kb + (kblk * 16 + lq) * 64;
            short8 bk0 = *(const short8*)(krow + (quad ^ sw) * 8);
            short8 bk1 = *(const short8*)(krow + ((quad + 4) ^ sw) * 8);
            floatx4 zA = (floatx4){0.f, 0.f, 0.f, 0.f};
            zA = __builtin_amdgcn_mfma_f32_16x16x32_bf16(bk0, qA0, zA, 0, 0, 0);
            sTA[kblk] = __builtin_amdgcn_mfma_f32_16x16x32_bf16(bk1, qA1, zA, 0, 0, 0);
            floatx4 zB = (floatx4){0.f, 0.f, 0.f, 0.f};
            zB = __builtin_amdgcn_mfma_f32_16x16x32_bf16(bk0, qB0, zB, 0, 0, 0);
            sTB[kblk] = __builtin_amdgcn_mfma_f32_16x16x32_bf16(bk1, qB1, zB, 0, 0, 0);
        }
        __builtin_amdgcn_s_setprio(0);

        // ---- no-max softmax + in-register P^T transpose + PV ----
        #pragma unroll
        for (int ts = 0; ts < 2; ++ts) {
            int ka = ts * 2, kc = ts * 2 + 1;
            // group A transpose
            unsigned int a00 = pack2bf(__builtin_amdgcn_exp2f(sTA[ka][0]),
                                       __builtin_amdgcn_exp2f(sTA[ka][1]));
            unsigned int a01 = pack2bf(__builtin_amdgcn_exp2f(sTA[ka][2]),
                                       __builtin_amdgcn_exp2f(sTA[ka][3]));
            unsigned int a10 = pack2bf(__builtin_amdgcn_exp2f(sTA[kc][0]),
                                       __builtin_amdgcn_exp2f(sTA[kc][1]));
            unsigned int a11 = pack2bf(__builtin_amdgcn_exp2f(sTA[kc][2]),
                                       __builtin_amdgcn_exp2f(sTA[kc][3]));
            uint2v sa0 = __builtin_amdgcn_permlane32_swap(a00, a10, false, false);
            uint2v sa1 = __builtin_amdgcn_permlane32_swap(a01, a11, false, false);
            uint2v wa02 = __builtin_amdgcn_permlane16_swap(sa0[0], sa0[1], false, false);
            uint2v wa13 = __builtin_amdgcn_permlane16_swap(sa1[0], sa1[1], false, false);
            union { unsigned int u[4]; short8 s8; } pfa;
            pfa.u[0] = wa02[0];
            pfa.u[1] = wa13[0];
            pfa.u[2] = wa02[1];
            pfa.u[3] = wa13[1];
            short8 pfA = pfa.s8;
            // group B transpose
            unsigned int b00 = pack2bf(__builtin_amdgcn_exp2f(sTB[ka][0]),
                                       __builtin_amdgcn_exp2f(sTB[ka][1]));
            unsigned int b01 = pack2bf(__builtin_amdgcn_exp2f(sTB[ka][2]),
                                       __builtin_amdgcn_exp2f(sTB[ka][3]));
            unsigned int b10 = pack2bf(__builtin_amdgcn_exp2f(sTB[kc][0]),
                                       __builtin_amdgcn_exp2f(sTB[kc][1]));
            unsigned int b11 = pack2bf(__builtin_amdgcn_exp2f(sTB[kc][2]),
                                       __builtin_amdgcn_exp2f(sTB[kc][3]));
            uint2v sb0 = __builtin_amdgcn_permlane32_swap(b00, b10, false, false);
            uint2v sb1 = __builtin_amdgcn_permlane32_swap(b01, b11, false, false);
            uint2v wb02 = __builtin_amdgcn_permlane16_swap(sb0[0], sb0[1], false, false);
            uint2v wb13 = __builtin_amdgcn_permlane16_swap(sb1[0], sb1[1], false, false);
            union { unsigned int u[4]; short8 s8; } pfb;
            pfb.u[0] = wb02[0];
            pfb.u[1] = wb13[0];
            pfb.u[2] = wb02[1];
            pfb.u[3] = wb13[1];
            short8 pfB = pfb.s8;

            __builtin_amdgcn_s_setprio(1);
            lsvA = __builtin_amdgcn_mfma_f32_16x16x32_bf16(ones, pfA, lsvA, 0, 0, 0);
            lsvB = __builtin_amdgcn_mfma_f32_16x16x32_bf16(ones, pfB, lsvB, 0, 0, 0);
            #pragma unroll
            for (int db = 0; db < 4; ++db) {
                const short* vrow = Vb + (db * 16 + lq) * 64;
                short8 bv = *(const short8*)(vrow + ((ts * 4 + quad) ^ sw) * 8);
                OA[db] = __builtin_amdgcn_mfma_f32_16x16x32_bf16(bv, pfA, OA[db], 0, 0, 0);
                OB[db] = __builtin_amdgcn_mfma_f32_16x16x32_bf16(bv, pfB, OB[db], 0, 0, 0);
            }
            __builtin_amdgcn_s_setprio(0);
        }

        p ^= 1;
    }

    // ---- epilogue: UNNORMALIZED bf16 partial O + fp32 row-sums ----
    short* dst = half ? zp1 : zp0;
    int sA = q0 + wave * 32 + lq;        // group A Q-row (lane-fixed)
    int sB = sA + 16;
    short* zrA = dst + (b * S_ + sA) * 640 + h * 64;
    short* zrB = dst + (b * S_ + sB) * 640 + h * 64;
    #pragma unroll
    for (int db = 0; db < 4; ++db) {
        uint2v za, zv;
        za[0] = pack2bf(OA[db][0], OA[db][1]);
        za[1] = pack2bf(OA[db][2], OA[db][3]);
        *(uint2v*)(zrA + db * 16 + quad * 4) = za;
        zv[0] = pack2bf(OB[db][0], OB[db][1]);
        zv[1] = pack2bf(OB[db][2], OB[db][3]);
        *(uint2v*)(zrB + db * 16 + quad * 4) = zv;
    }
    if (quad == 0) {
        float* lp = lsvb + half * (B_ * H_ * S_) + (b * H_ + h) * S_;
        lp[sA] = lsvA[0];
        lp[sB] = lsvB[0];
    }
}

// ---------------------------------------------------------------------------
// Kernel 3b: combine — z = (P0 + P1) / (lsv0 + lsv1), in place over zp0=zb.
// 655,360 threads x 8 bf16 each; 8-elem groups never straddle an h-block.
// ---------------------------------------------------------------------------
__global__ __launch_bounds__(256) void combine(
        const short* __restrict__ zp1, const float* __restrict__ lsvb,
        short* __restrict__ zb) {
    int idx = blockIdx.x * 256 + threadIdx.x;   // [0, 655360)
    int row = idx / 80;                         // 80 groups of 8 per row
    int col = (idx - row * 80) * 8;
    int b = row >> 11, s = row & 2047;
    int h = col >> 6;
    int li = (b * H_ + h) * S_ + s;
    float inv = 1.0f / (lsvb[li] + lsvb[B_ * H_ * S_ + li]);

    const short* a0 = zb  + row * 640 + col;
    const short* a1 = zp1 + row * 640 + col;
    short8 p0 = *(const short8*)a0;
    short8 p1 = *(const short8*)a1;
    float f[8];
    #pragma unroll
    for (int i = 0; i < 8; ++i)
        f[i] = (bf2f(p0[i]) + bf2f(p1[i])) * inv;
    uint4v o;
    o[0] = pack2bf(f[0], f[1]);
    o[1] = pack2bf(f[2], f[3]);
    o[2] = pack2bf(f[4], f[5]);
    o[3] = pack2bf(f[6], f[7]);
    *(uint4v*)(zb + row * 640 + col) = o;
}

// ---------------------------------------------------------------------------
// Kernel 4: output projection, 128(M)x64(N) tile, grid 640.  out = Z @ WoT^T.
// SWAPPED mfma -> r runs along contiguous out columns -> float4 stores.
// ---------------------------------------------------------------------------
__global__ __launch_bounds__(256) void out_gemm(
        const short* __restrict__ Z, const short* __restrict__ WoT,
        float* __restrict__ out) {
    __shared__ __align__(16) short Ab[2][128][32];   // 16 KB
    __shared__ __align__(16) short Bb[2][64][32];    //  8 KB

    int wave = threadIdx.x >> 6;
    int lane = threadIdx.x & 63;
    int lq = lane & 15, quad = lane >> 4;
    int wm = (wave & 1) * 64;        // M offset within tile
    int wn = (wave >> 1) * 32;       // N offset within tile

    int lin = blockIdx.y * 64 + blockIdx.x;          // [0, 640)
    int tm = ((lin & 7) * 8 + ((lin >> 3) & 7)) * 128;
    int tn = (lin >> 6) * 64;

    int srow = lane >> 2;
    int schunk = (lane & 3) ^ ((lane >> 3) & 3);
    const short* Asrc0 = Z   + (tm + wave * 32 + srow) * 640 + schunk * 8;
    const short* Asrc1 = Asrc0 + 16 * 640;
    const short* Bsrc0 = WoT + (tn + wave * 16 + srow) * 640 + schunk * 8;

    floatx4 acc[4][2];
    for (int a = 0; a < 4; ++a)
        for (int n = 0; n < 2; ++n)
            acc[a][n] = (floatx4){0.f, 0.f, 0.f, 0.f};

    int rsw = (lq >> 1) & 3;

    gload_lds16(Asrc0, &Ab[0][wave * 32][0]);
    gload_lds16(Asrc1, &Ab[0][wave * 32 + 16][0]);
    gload_lds16(Bsrc0, &Bb[0][wave * 16][0]);

    int p = 0;
    for (int k0 = 0; k0 < 640; k0 += 32) {
        __syncthreads();
        if (k0 + 32 < 640) {
            int pn = p ^ 1;
            gload_lds16(Asrc0 + k0 + 32, &Ab[pn][wave * 32][0]);
            gload_lds16(Asrc1 + k0 + 32, &Ab[pn][wave * 32 + 16][0]);
            gload_lds16(Bsrc0 + k0 + 32, &Bb[pn][wave * 16][0]);
        }

        short8 af[4], bf[2];
        #pragma unroll
        for (int t = 0; t < 4; ++t)
            af[t] = *(const short8*)(&Ab[p][wm + t * 16 + lq][(quad ^ rsw) * 8]);
        #pragma unroll
        for (int u = 0; u < 2; ++u)
            bf[u] = *(const short8*)(&Bb[p][wn + u * 16 + lq][(quad ^ rsw) * 8]);
        // SWAPPED: col(lq)=m, row(quad*4+r)=n
        #pragma unroll
        for (int mt = 0; mt < 4; ++mt)
            #pragma unroll
            for (int nt = 0; nt < 2; ++nt)
                acc[mt][nt] = __builtin_amdgcn_mfma_f32_16x16x32_bf16(
                    bf[nt], af[mt], acc[mt][nt], 0, 0, 0);
        p ^= 1;
    }

    #pragma unroll
    for (int mt = 0; mt < 4; ++mt) {
        int m = tm + wm + mt * 16 + lq;
        #pragma unroll
        for (int nt = 0; nt < 2; ++nt) {
            int n0 = tn + wn + nt * 16 + quad * 4;
            float4 v;
            v.x = acc[mt][nt][0];
            v.y = acc[mt][nt][1];
            v.z = acc[mt][nt][2];
            v.w = acc[mt][nt][3];
            *(float4*)(out + m * 640 + n0) = v;
        }
    }
}

// ---------------------------------------------------------------------------
extern "C" void kernel_launch(void* const* d_in, const int* in_sizes, int n_in,
                              void* d_out, int out_size, void* d_ws, size_t ws_size,
                              hipStream_t stream) {
    const float* x  = (const float*)d_in[0];
    const float* Wq = (const float*)d_in[1];
    const float* Wk = (const float*)d_in[2];
    const float* Wv = (const float*)d_in[3];
    const float* Wo = (const float*)d_in[4];
    float* out = (float*)d_out;

    char* ws = (char*)d_ws;
    short* BigT = (short*)(ws);                    //  1920*640*2 = 2,457,600
    short* WoT  = (short*)(ws + 2457600);          //   640*640*2 =   819,200
    short* xb   = (short*)(ws + 3276800);          // 8192*640*2  = 10,485,760
    short* qb   = (short*)(ws + 13762560);
    short* kb   = (short*)(ws + 24248320);
    short* vtb  = (short*)(ws + 34734080);
    short* zb   = (short*)(ws + 45219840);         // end = 55,705,600 B
    // dead-space reuse during/after attn:
    //   P1 partial  -> xb region   (xb dead after qkv_gemm)
    //   lsv partials-> BigT region (dead after qkv_gemm; 2*81920*4 = 655 KB)
    //   P0 partial  -> zb (combined in place)
    short* zp1  = xb;
    float* lsvb = (float*)ws;

    prep<<<dim3(6720), dim3(256), 0, stream>>>(x, Wq, Wk, Wv, Wo, xb, BigT, WoT);
    qkv_gemm<<<dim3(64, 15), dim3(256), 0, stream>>>(xb, BigT, qb, kb, vtb);
    attn<<<dim3(1280), dim3(256), 0, stream>>>(qb, kb, vtb, zb, zp1, lsvb);
    combine<<<dim3(2560), dim3(256), 0, stream>>>(zp1, lsvb, zb);
    out_gemm<<<dim3(64, 10), dim3(256), 0, stream>>>(zb, WoT, out);
}